// Round 1
// baseline (5864.396 us; speedup 1.0000x reference)
//
#include <hip/hip_runtime.h>
#include <stdint.h>

#define T_ 128
#define B_ 256
#define D_ 512
#define H_ 768
#define NG 3072   // 4*H
#define OUT_ 60

// phase-C decomposition: 4 batch groups (64 rows) x 48 strips (16 h-cols) = 192 WGs
#define GRP_WGS 48

using bf16x8 = __attribute__((ext_vector_type(8))) __bf16;
using f32x4  = __attribute__((ext_vector_type(4))) float;

// ---------------- ws layout (bytes) ----------------
#define OFF_XBF  ((size_t)0)                       // ushort[T*B*D]   x as bf16
#define OFF_WIH  (OFF_XBF + (size_t)T_*B_*D_*2)    // ushort[NG*D]    W_ih bf16
#define OFF_WHH  (OFF_WIH + (size_t)NG*D_*2)       // ushort[NG*H]    W_hh bf16
#define OFF_H    (OFF_WHH + (size_t)NG*H_*2)       // ushort[2*B*H]   h double buffer
#define OFF_HT   (OFF_H   + (size_t)2*B_*H_*2)     // float[B*H]      final h (fp32)
#define OFF_BAR  (OFF_HT  + (size_t)B_*H_*4)       // uint[64]        group barriers
#define OFF_XP   (OFF_BAR + 256)                   // ushort[T*B*NG]  x-projection bf16
#define WS_PRE   (OFF_XP  + (size_t)T_*B_*NG*2)    // ~233 MB

__device__ __forceinline__ unsigned short f2bf(float f) {
  union { float f; unsigned u; } v; v.f = f;
  unsigned r = (v.u + 0x7fffu + ((v.u >> 16) & 1u)) >> 16;  // RNE
  return (unsigned short)r;
}
__device__ __forceinline__ float bf2f(unsigned short s) {
  union { unsigned u; float f; } v; v.u = ((unsigned)s) << 16;
  return v.f;
}
__device__ __forceinline__ float sigf(float x) {
  return __builtin_amdgcn_rcpf(1.0f + __expf(-x));
}
__device__ __forceinline__ float tanhf_(float x) {
  return 2.0f * __builtin_amdgcn_rcpf(1.0f + __expf(-2.0f * x)) - 1.0f;
}
__device__ __forceinline__ void gload16(const void* g, void* l) {
  __builtin_amdgcn_global_load_lds(
      (const __attribute__((address_space(1))) unsigned int*)g,
      (__attribute__((address_space(3))) unsigned int*)l, 16, 0, 0);
}

// ---------------- phase A: convert + init ----------------
__global__ void prep_kernel(const float* __restrict__ x,
                            const float* __restrict__ wihf,
                            const float* __restrict__ whhf,
                            uint8_t* __restrict__ ws) {
  ushort* xb = (ushort*)(ws + OFF_XBF);
  ushort* wi = (ushort*)(ws + OFF_WIH);
  ushort* wh = (ushort*)(ws + OFF_WHH);
  unsigned* hb = (unsigned*)(ws + OFF_H);
  unsigned* bar = (unsigned*)(ws + OFF_BAR);
  const size_t tid = (size_t)blockIdx.x * blockDim.x + threadIdx.x;
  const size_t nth = (size_t)gridDim.x * blockDim.x;
  for (size_t i = tid; i < (size_t)T_*B_*D_/4; i += nth) {
    float4 v = ((const float4*)x)[i];
    ushort4 o; o.x=f2bf(v.x); o.y=f2bf(v.y); o.z=f2bf(v.z); o.w=f2bf(v.w);
    ((ushort4*)xb)[i] = o;
  }
  for (size_t i = tid; i < (size_t)NG*D_/4; i += nth) {
    float4 v = ((const float4*)wihf)[i];
    ushort4 o; o.x=f2bf(v.x); o.y=f2bf(v.y); o.z=f2bf(v.z); o.w=f2bf(v.w);
    ((ushort4*)wi)[i] = o;
  }
  for (size_t i = tid; i < (size_t)NG*H_/4; i += nth) {
    float4 v = ((const float4*)whhf)[i];
    ushort4 o; o.x=f2bf(v.x); o.y=f2bf(v.y); o.z=f2bf(v.z); o.w=f2bf(v.w);
    ((ushort4*)wh)[i] = o;
  }
  for (size_t i = tid; i < (size_t)2*B_*H_/2; i += nth) hb[i] = 0u;  // h buffers = 0
  if (tid < 64) bar[tid] = 0u;
}

// ---------------- phase B: xp = x @ W_ih^T (bf16 MFMA, 128x128 tile, BK=64) ----------------
__global__ __launch_bounds__(256) void xproj_kernel(uint8_t* __restrict__ ws) {
  const ushort* __restrict__ xb = (const ushort*)(ws + OFF_XBF);
  const ushort* __restrict__ wi = (const ushort*)(ws + OFF_WIH);
  ushort* __restrict__ xp = (ushort*)(ws + OFF_XP);

  __shared__ ushort smA[128*64];  // [128][64] bf16, XOR-swizzled (bits 4-6 ^ row&7)
  __shared__ ushort smB[128*64];

  const int tid = threadIdx.x;
  const int lane = tid & 63;
  const int w = tid >> 6;
  const int bn = blockIdx.x % 24;
  const int bm = blockIdx.x / 24;
  const int m0 = bm * 128, n0 = bn * 128;
  const int mi = (w >> 1) * 64, ni = (w & 1) * 64;

  f32x4 acc[4][4] = {};

  for (int k0 = 0; k0 < D_; k0 += 64) {
    __syncthreads();
    #pragma unroll
    for (int i = 0; i < 4; ++i) {
      const int ig = w*4 + i;                 // wave-uniform
      const int o  = ig*1024 + lane*16;       // lds byte this lane fills
      const int row = o >> 7;                 // /128B per row
      const int colB = o & 127;
      const int scol = colB ^ ((row & 7) << 4);  // pre-swizzled source (m173)
      gload16((const uint8_t*)xb + ((size_t)(m0+row)*D_ + k0)*2 + scol,
              (uint8_t*)smA + ig*1024);
      gload16((const uint8_t*)wi + ((size_t)(n0+row)*D_ + k0)*2 + scol,
              (uint8_t*)smB + ig*1024);
    }
    __syncthreads();
    #pragma unroll
    for (int kk = 0; kk < 2; ++kk) {
      const int colB = kk*64 + (lane >> 4)*16;
      bf16x8 a[4], b[4];
      #pragma unroll
      for (int mt = 0; mt < 4; ++mt) {
        const int row = mi + mt*16 + (lane & 15);
        a[mt] = *(const bf16x8*)((const uint8_t*)smA + row*128 + (colB ^ ((row & 7) << 4)));
      }
      #pragma unroll
      for (int nt = 0; nt < 4; ++nt) {
        const int row = ni + nt*16 + (lane & 15);
        b[nt] = *(const bf16x8*)((const uint8_t*)smB + row*128 + (colB ^ ((row & 7) << 4)));
      }
      #pragma unroll
      for (int mt = 0; mt < 4; ++mt)
        #pragma unroll
        for (int nt = 0; nt < 4; ++nt)
          acc[mt][nt] = __builtin_amdgcn_mfma_f32_16x16x32_bf16(a[mt], b[nt], acc[mt][nt], 0, 0, 0);
    }
  }
  // store bf16 (C/D layout: col = lane&15, row = (lane>>4)*4 + reg  [m89-verified])
  #pragma unroll
  for (int mt = 0; mt < 4; ++mt)
    #pragma unroll
    for (int nt = 0; nt < 4; ++nt) {
      const int r0 = m0 + mi + mt*16 + (lane >> 4)*4;
      const int c  = n0 + ni + nt*16 + (lane & 15);
      #pragma unroll
      for (int r = 0; r < 4; ++r)
        xp[(size_t)(r0 + r)*NG + c] = f2bf(acc[mt][nt][r]);
    }
}

// ---------------- phase C: persistent recurrence ----------------
template<bool PRE>
__global__ __launch_bounds__(256) void lstm_kernel(uint8_t* __restrict__ ws,
                                                   const float* __restrict__ bih,
                                                   const float* __restrict__ bhh) {
  const ushort* __restrict__ xb = (const ushort*)(ws + OFF_XBF);
  const ushort* __restrict__ wi = (const ushort*)(ws + OFF_WIH);
  const ushort* __restrict__ wh = (const ushort*)(ws + OFF_WHH);
  const ushort* __restrict__ xp = (const ushort*)(ws + OFF_XP);
  ushort* __restrict__ hb = (ushort*)(ws + OFF_H);
  float* __restrict__ hT = (float*)(ws + OFF_HT);
  unsigned* bar = (unsigned*)(ws + OFF_BAR);

  const int tid = threadIdx.x;
  const int lane = tid & 63;
  const int w = tid >> 6;                 // wave 0..3 -> 16 batch rows each
  const int g = blockIdx.x & 3;           // batch group (also spreads groups over XCD pairs)
  const int s = blockIdx.x >> 2;          // h-strip 0..47
  const int rb0 = g * 64;
  const int colj = s*16 + (lane & 15);    // owned h column (B/C col = lane&15)
  const int arow = rb0 + w*16 + (lane & 15);     // A-frag row (batch)
  const int crow = rb0 + w*16 + (lane >> 4)*4;   // C rows base
  const int ak = (lane >> 4) * 8;                // A/B k-offset (elements)

  // W_hh rows for gates 0,1 live in LDS for all 128 steps (fence-immune), swizzled
  __shared__ ushort wlds[32*768];  // 48 KB
  for (int c = tid; c < 32*96; c += 256) {       // 16B chunks
    const int row = c / 96;                      // 0..31 = gate q (=row>>4) col j (=row&15)
    const int colB = (c % 96) * 16;
    const uint4 v = *(const uint4*)((const uint8_t*)wh +
        ((size_t)((row >> 4)*H_ + s*16 + (row & 15))*H_)*2 + colB);
    *(uint4*)((uint8_t*)wlds + row*1536 + (colB ^ ((row & 7) << 4))) = v;
  }
  __syncthreads();

  float bias[4];
  #pragma unroll
  for (int q = 0; q < 4; ++q) bias[q] = bih[q*H_ + colj] + bhh[q*H_ + colj];

  const ushort* wB2 = wh + (size_t)(2*H_ + colj)*H_ + ak;  // gates 2,3 from L2
  const ushort* wB3 = wh + (size_t)(3*H_ + colj)*H_ + ak;
  const ushort* wI[4];
  #pragma unroll
  for (int q = 0; q < 4; ++q) wI[q] = wi + (size_t)(q*H_ + colj)*D_ + ak;

  float cc[4] = {0.f, 0.f, 0.f, 0.f};

  for (int t = 0; t < T_; ++t) {
    f32x4 acc[4];
    if (PRE) {
      const ushort* xpt = xp + ((size_t)(t*B_ + crow))*NG;
      #pragma unroll
      for (int q = 0; q < 4; ++q) {
        const int n = q*H_ + colj;
        f32x4 a;
        #pragma unroll
        for (int r = 0; r < 4; ++r) a[r] = bf2f(xpt[(size_t)r*NG + n]);
        acc[q] = a;
      }
    } else {
      #pragma unroll
      for (int q = 0; q < 4; ++q) acc[q] = (f32x4){0.f,0.f,0.f,0.f};
      const ushort* xrow = xb + ((size_t)(t*B_ + arow))*D_ + ak;
      #pragma unroll 4
      for (int k0 = 0; k0 < D_; k0 += 32) {
        bf16x8 a = *(const bf16x8*)(xrow + k0);
        #pragma unroll
        for (int q = 0; q < 4; ++q) {
          bf16x8 b = *(const bf16x8*)(wI[q] + k0);
          acc[q] = __builtin_amdgcn_mfma_f32_16x16x32_bf16(a, b, acc[q], 0, 0, 0);
        }
      }
    }
    // recurrent GEMM: gates[q] += h @ W_hh[q-strip]^T
    const ushort* hrow = hb + (size_t)(t & 1)*B_*H_ + (size_t)arow*H_ + ak;
    #pragma unroll 4
    for (int k0 = 0; k0 < H_; k0 += 32) {
      bf16x8 a = *(const bf16x8*)(hrow + k0);
      const int colB = k0*2 + (lane >> 4)*16;
      #pragma unroll
      for (int q = 0; q < 2; ++q) {
        const int brow = q*16 + (lane & 15);
        bf16x8 b = *(const bf16x8*)((const uint8_t*)wlds + brow*1536 + (colB ^ ((brow & 7) << 4)));
        acc[q] = __builtin_amdgcn_mfma_f32_16x16x32_bf16(a, b, acc[q], 0, 0, 0);
      }
      bf16x8 b2 = *(const bf16x8*)(wB2 + k0);
      acc[2] = __builtin_amdgcn_mfma_f32_16x16x32_bf16(a, b2, acc[2], 0, 0, 0);
      bf16x8 b3 = *(const bf16x8*)(wB3 + k0);
      acc[3] = __builtin_amdgcn_mfma_f32_16x16x32_bf16(a, b3, acc[3], 0, 0, 0);
    }
    // gate activations + state update (each lane owns 4 (row,col) cells, all 4 gates local)
    ushort* hn = hb + (size_t)((t+1) & 1)*B_*H_;
    #pragma unroll
    for (int r = 0; r < 4; ++r) {
      const float iv = sigf(acc[0][r] + bias[0]);
      const float fv = sigf(acc[1][r] + bias[1]);
      const float gv = tanhf_(acc[2][r] + bias[2]);
      const float ov = sigf(acc[3][r] + bias[3]);
      const float cn = fv * cc[r] + iv * gv;
      cc[r] = cn;
      const float hv = ov * tanhf_(cn);
      hn[(size_t)(crow + r)*H_ + colj] = f2bf(hv);
      if (t == T_-1) hT[(size_t)(crow + r)*H_ + colj] = hv;
    }
    if (t < T_-1) {
      // group barrier: monotonic counter, release/acquire at agent scope
      __threadfence();      // publish this thread's h stores agent-wide
      __syncthreads();
      if (tid == 0) {
        __hip_atomic_fetch_add(&bar[g], 1u, __ATOMIC_RELEASE, __HIP_MEMORY_SCOPE_AGENT);
        const unsigned tgt = (unsigned)GRP_WGS * (unsigned)(t + 1);
        while (__hip_atomic_load(&bar[g], __ATOMIC_ACQUIRE, __HIP_MEMORY_SCOPE_AGENT) < tgt)
          __builtin_amdgcn_s_sleep(2);
      }
      __syncthreads();
      __threadfence();      // acquire: invalidate stale h lines in L1/L2
    }
  }
}

// ---------------- phase D: out = h_T @ W_fc^T + b_fc ----------------
__global__ __launch_bounds__(64) void fc_kernel(const uint8_t* __restrict__ ws,
                                                const float* __restrict__ wfc,
                                                const float* __restrict__ bfc,
                                                float* __restrict__ out) {
  const float* hT = (const float*)(ws + OFF_HT);
  const int b = blockIdx.x;
  const int lane = threadIdx.x;
  const float* hr = hT + (size_t)b*H_;
  float hv[12];
  #pragma unroll
  for (int i = 0; i < 12; ++i) hv[i] = hr[lane + i*64];
  for (int o = 0; o < OUT_; ++o) {
    const float* wr = wfc + (size_t)o*H_;
    float sum = 0.f;
    #pragma unroll
    for (int i = 0; i < 12; ++i) sum += hv[i] * wr[lane + i*64];
    #pragma unroll
    for (int off = 32; off; off >>= 1) sum += __shfl_xor(sum, off);
    if (lane == 0) out[(size_t)b*OUT_ + o] = sum + bfc[o];
  }
}

extern "C" void kernel_launch(void* const* d_in, const int* in_sizes, int n_in,
                              void* d_out, int out_size, void* d_ws, size_t ws_size,
                              hipStream_t stream) {
  const float* x   = (const float*)d_in[0];
  const float* wih = (const float*)d_in[1];
  const float* whh = (const float*)d_in[2];
  const float* bih = (const float*)d_in[3];
  const float* bhh = (const float*)d_in[4];
  const float* wfc = (const float*)d_in[5];
  const float* bfc = (const float*)d_in[6];
  uint8_t* ws = (uint8_t*)d_ws;
  float* out = (float*)d_out;

  const bool pre = (ws_size >= WS_PRE);  // deterministic per-session

  prep_kernel<<<dim3(2048), dim3(256), 0, stream>>>(x, wih, whh, ws);
  if (pre) {
    xproj_kernel<<<dim3(256*24), dim3(256), 0, stream>>>(ws);
    lstm_kernel<true><<<dim3(192), dim3(256), 0, stream>>>(ws, bih, bhh);
  } else {
    lstm_kernel<false><<<dim3(192), dim3(256), 0, stream>>>(ws, bih, bhh);
  }
  fc_kernel<<<dim3(256), dim3(64), 0, stream>>>(ws, wfc, bfc, out);
}

// Round 2
// 1433.764 us; speedup vs baseline: 4.0902x; 4.0902x over previous
//
#include <hip/hip_runtime.h>
#include <stdint.h>

#define T_ 128
#define B_ 256
#define D_ 512
#define H_ 768
#define NG 3072   // 4*H
#define OUT_ 60

// phase-C decomposition: 4 batch groups (64 rows) x 48 strips (16 h-cols) = 192 WGs
#define GRP_WGS 48

using bf16x8 = __attribute__((ext_vector_type(8))) __bf16;
using f32x4  = __attribute__((ext_vector_type(4))) float;

// ---------------- ws layout (bytes) ----------------
#define OFF_XBF  ((size_t)0)                       // ushort[T*B*D]   x as bf16
#define OFF_WIH  (OFF_XBF + (size_t)T_*B_*D_*2)    // ushort[NG*D]    W_ih bf16
#define OFF_WHH  (OFF_WIH + (size_t)NG*D_*2)       // ushort[NG*H]    W_hh bf16
#define OFF_H    (OFF_WHH + (size_t)NG*H_*2)       // ushort[2*B*H]   h double buffer
#define OFF_HT   (OFF_H   + (size_t)2*B_*H_*2)     // float[B*H]      final h (fp32)
#define OFF_BAR  (OFF_HT  + (size_t)B_*H_*4)       // uint[64]        group barriers (spread)
#define OFF_XP   (OFF_BAR + 256)                   // ushort[T*B*NG]  x-projection bf16
#define WS_PRE   (OFF_XP  + (size_t)T_*B_*NG*2)    // ~242 MB

__device__ __forceinline__ unsigned short f2bf(float f) {
  union { float f; unsigned u; } v; v.f = f;
  unsigned r = (v.u + 0x7fffu + ((v.u >> 16) & 1u)) >> 16;  // RNE
  return (unsigned short)r;
}
__device__ __forceinline__ float bf2f(unsigned short s) {
  union { unsigned u; float f; } v; v.u = ((unsigned)s) << 16;
  return v.f;
}
__device__ __forceinline__ float sigf(float x) {
  return __builtin_amdgcn_rcpf(1.0f + __expf(-x));
}
__device__ __forceinline__ float tanhf_(float x) {
  return 2.0f * __builtin_amdgcn_rcpf(1.0f + __expf(-2.0f * x)) - 1.0f;
}
__device__ __forceinline__ void gload16(const void* g, void* l) {
  __builtin_amdgcn_global_load_lds(
      (const __attribute__((address_space(1))) unsigned int*)g,
      (__attribute__((address_space(3))) unsigned int*)l, 16, 0, 0);
}
// coherent 8B ops: relaxed system scope -> sc0 sc1 (bypass L1/L2, coherence point),
// NO cache-wide flush/invalidate (the R0 fence killer).
__device__ __forceinline__ void coh_store8(void* p, unsigned long long v) {
  __hip_atomic_store((unsigned long long*)p, v, __ATOMIC_RELAXED, __HIP_MEMORY_SCOPE_SYSTEM);
}
__device__ __forceinline__ unsigned long long coh_load8(const void* p) {
  return __hip_atomic_load((const unsigned long long*)p, __ATOMIC_RELAXED, __HIP_MEMORY_SCOPE_SYSTEM);
}

// ---------------- phase A: convert + init ----------------
__global__ void prep_kernel(const float* __restrict__ x,
                            const float* __restrict__ wihf,
                            const float* __restrict__ whhf,
                            uint8_t* __restrict__ ws) {
  ushort* xb = (ushort*)(ws + OFF_XBF);
  ushort* wi = (ushort*)(ws + OFF_WIH);
  ushort* wh = (ushort*)(ws + OFF_WHH);
  unsigned* hb = (unsigned*)(ws + OFF_H);
  unsigned* bar = (unsigned*)(ws + OFF_BAR);
  const size_t tid = (size_t)blockIdx.x * blockDim.x + threadIdx.x;
  const size_t nth = (size_t)gridDim.x * blockDim.x;
  for (size_t i = tid; i < (size_t)T_*B_*D_/4; i += nth) {
    float4 v = ((const float4*)x)[i];
    ushort4 o; o.x=f2bf(v.x); o.y=f2bf(v.y); o.z=f2bf(v.z); o.w=f2bf(v.w);
    ((ushort4*)xb)[i] = o;
  }
  for (size_t i = tid; i < (size_t)NG*D_/4; i += nth) {
    float4 v = ((const float4*)wihf)[i];
    ushort4 o; o.x=f2bf(v.x); o.y=f2bf(v.y); o.z=f2bf(v.z); o.w=f2bf(v.w);
    ((ushort4*)wi)[i] = o;
  }
  for (size_t i = tid; i < (size_t)NG*H_/4; i += nth) {
    float4 v = ((const float4*)whhf)[i];
    ushort4 o; o.x=f2bf(v.x); o.y=f2bf(v.y); o.z=f2bf(v.z); o.w=f2bf(v.w);
    ((ushort4*)wh)[i] = o;
  }
  for (size_t i = tid; i < (size_t)2*B_*H_/2; i += nth) hb[i] = 0u;  // h buffers = 0
  if (tid < 64) bar[tid] = 0u;
}

// ---------------- phase B: xp = x @ W_ih^T (bf16 MFMA, 128x128 tile, BK=64) ----------------
__global__ __launch_bounds__(256) void xproj_kernel(uint8_t* __restrict__ ws) {
  const ushort* __restrict__ xb = (const ushort*)(ws + OFF_XBF);
  const ushort* __restrict__ wi = (const ushort*)(ws + OFF_WIH);
  ushort* __restrict__ xp = (ushort*)(ws + OFF_XP);

  __shared__ ushort smA[128*64];  // [128][64] bf16, XOR-swizzled (bits 4-6 ^ row&7)
  __shared__ ushort smB[128*64];

  const int tid = threadIdx.x;
  const int lane = tid & 63;
  const int w = tid >> 6;
  const int bn = blockIdx.x % 24;
  const int bm = blockIdx.x / 24;
  const int m0 = bm * 128, n0 = bn * 128;
  const int mi = (w >> 1) * 64, ni = (w & 1) * 64;

  f32x4 acc[4][4] = {};

  for (int k0 = 0; k0 < D_; k0 += 64) {
    __syncthreads();
    #pragma unroll
    for (int i = 0; i < 4; ++i) {
      const int ig = w*4 + i;                 // wave-uniform
      const int o  = ig*1024 + lane*16;       // lds byte this lane fills
      const int row = o >> 7;                 // /128B per row
      const int colB = o & 127;
      const int scol = colB ^ ((row & 7) << 4);  // pre-swizzled source (m173)
      gload16((const uint8_t*)xb + ((size_t)(m0+row)*D_ + k0)*2 + scol,
              (uint8_t*)smA + ig*1024);
      gload16((const uint8_t*)wi + ((size_t)(n0+row)*D_ + k0)*2 + scol,
              (uint8_t*)smB + ig*1024);
    }
    __syncthreads();
    #pragma unroll
    for (int kk = 0; kk < 2; ++kk) {
      const int colB = kk*64 + (lane >> 4)*16;
      bf16x8 a[4], b[4];
      #pragma unroll
      for (int mt = 0; mt < 4; ++mt) {
        const int row = mi + mt*16 + (lane & 15);
        a[mt] = *(const bf16x8*)((const uint8_t*)smA + row*128 + (colB ^ ((row & 7) << 4)));
      }
      #pragma unroll
      for (int nt = 0; nt < 4; ++nt) {
        const int row = ni + nt*16 + (lane & 15);
        b[nt] = *(const bf16x8*)((const uint8_t*)smB + row*128 + (colB ^ ((row & 7) << 4)));
      }
      #pragma unroll
      for (int mt = 0; mt < 4; ++mt)
        #pragma unroll
        for (int nt = 0; nt < 4; ++nt)
          acc[mt][nt] = __builtin_amdgcn_mfma_f32_16x16x32_bf16(a[mt], b[nt], acc[mt][nt], 0, 0, 0);
    }
  }
  // store bf16 (C/D layout: col = lane&15, row = (lane>>4)*4 + reg  [m89-verified])
  #pragma unroll
  for (int mt = 0; mt < 4; ++mt)
    #pragma unroll
    for (int nt = 0; nt < 4; ++nt) {
      const int r0 = m0 + mi + mt*16 + (lane >> 4)*4;
      const int c  = n0 + ni + nt*16 + (lane & 15);
      #pragma unroll
      for (int r = 0; r < 4; ++r)
        xp[(size_t)(r0 + r)*NG + c] = f2bf(acc[mt][nt][r]);
    }
}

// ---------------- phase C: persistent recurrence ----------------
// 192 WGs (1/CU, LDS-capped), 4 groups x 48 strips. ALL W_hh slices in LDS;
// only h crosses memory, via relaxed system-scope 8B atomics (no cache flushes).
template<bool PRE>
__global__ __launch_bounds__(256) void lstm_kernel(uint8_t* __restrict__ ws,
                                                   const float* __restrict__ bih,
                                                   const float* __restrict__ bhh) {
  const ushort* __restrict__ xb = (const ushort*)(ws + OFF_XBF);
  const ushort* __restrict__ wi = (const ushort*)(ws + OFF_WIH);
  const ushort* __restrict__ wh = (const ushort*)(ws + OFF_WHH);
  const ushort* __restrict__ xp = (const ushort*)(ws + OFF_XP);
  ushort* __restrict__ hb = (ushort*)(ws + OFF_H);
  float* __restrict__ hT = (float*)(ws + OFF_HT);
  unsigned* bar = (unsigned*)(ws + OFF_BAR);

  const int tid = threadIdx.x;
  const int lane = tid & 63;
  const int w = tid >> 6;                 // wave 0..3 -> 16 batch rows each
  const int g = blockIdx.x & 3;           // batch group
  const int s = blockIdx.x >> 2;          // h-strip 0..47
  const int rb0 = g * 64;
  const int colj = s*16 + (lane & 15);    // owned h column (B/C col = lane&15)
  const int arow = rb0 + w*16 + (lane & 15);     // A-frag row (batch)
  const int crowl = w*16 + (lane >> 4)*4;        // C rows base (group-local)
  const int ak = (lane >> 4) * 8;                // A/B k-offset (elements)

  // all 4 gates' W_hh rows in LDS for all 128 steps, XOR-swizzled. 96 KB.
  __shared__ ushort wlds[64*768];
  __shared__ ushort hstage[64*16];  // 2 KB repack buffer for coherent 8B h-stores
  for (int c = tid; c < 64*96; c += 256) {       // 16B chunks
    const int row = c / 96;                      // gate q = row>>4, col j = row&15
    const int colB = (c % 96) * 16;
    const uint4 v = *(const uint4*)((const uint8_t*)wh +
        ((size_t)((row >> 4)*H_ + s*16 + (row & 15))*H_)*2 + colB);
    *(uint4*)((uint8_t*)wlds + row*1536 + (colB ^ ((row & 7) << 4))) = v;
  }
  __syncthreads();

  float bias[4];
  #pragma unroll
  for (int q = 0; q < 4; ++q) bias[q] = bih[q*H_ + colj] + bhh[q*H_ + colj];

  const ushort* wI[4];
  #pragma unroll
  for (int q = 0; q < 4; ++q) wI[q] = wi + (size_t)(q*H_ + colj)*D_ + ak;

  float cc[4] = {0.f, 0.f, 0.f, 0.f};

  for (int t = 0; t < T_; ++t) {
    f32x4 acc[4];
    if (PRE) {
      const ushort* xpt = xp + ((size_t)(t*B_ + rb0 + crowl))*NG;
      #pragma unroll
      for (int q = 0; q < 4; ++q) {
        const int n = q*H_ + colj;
        f32x4 a;
        #pragma unroll
        for (int r = 0; r < 4; ++r) a[r] = bf2f(xpt[(size_t)r*NG + n]);
        acc[q] = a;
      }
    } else {
      #pragma unroll
      for (int q = 0; q < 4; ++q) acc[q] = (f32x4){0.f,0.f,0.f,0.f};
      const ushort* xrow = xb + ((size_t)(t*B_ + arow))*D_ + ak;
      #pragma unroll 4
      for (int k0 = 0; k0 < D_; k0 += 32) {
        bf16x8 a = *(const bf16x8*)(xrow + k0);
        #pragma unroll
        for (int q = 0; q < 4; ++q) {
          bf16x8 b = *(const bf16x8*)(wI[q] + k0);
          acc[q] = __builtin_amdgcn_mfma_f32_16x16x32_bf16(a, b, acc[q], 0, 0, 0);
        }
      }
    }
    // recurrent GEMM: gates[q] += h @ W_hh[q-strip]^T ; h via coherent 8B loads
    const ushort* hrow = hb + (size_t)(t & 1)*B_*H_ + (size_t)arow*H_ + ak;
    #pragma unroll 4
    for (int k0 = 0; k0 < H_; k0 += 32) {
      union { unsigned long long u[2]; bf16x8 v; } au;
      au.u[0] = coh_load8(hrow + k0);
      au.u[1] = coh_load8(hrow + k0 + 4);
      const bf16x8 a = au.v;
      const int colB = k0*2 + (lane >> 4)*16;
      #pragma unroll
      for (int q = 0; q < 4; ++q) {
        const int brow = q*16 + (lane & 15);
        bf16x8 b = *(const bf16x8*)((const uint8_t*)wlds + brow*1536 + (colB ^ ((brow & 7) << 4)));
        acc[q] = __builtin_amdgcn_mfma_f32_16x16x32_bf16(a, b, acc[q], 0, 0, 0);
      }
    }
    // gate activations + state update (each lane owns 4 (row,col) cells, all 4 gates local)
    #pragma unroll
    for (int r = 0; r < 4; ++r) {
      const float iv = sigf(acc[0][r] + bias[0]);
      const float fv = sigf(acc[1][r] + bias[1]);
      const float gv = tanhf_(acc[2][r] + bias[2]);
      const float ov = sigf(acc[3][r] + bias[3]);
      const float cn = fv * cc[r] + iv * gv;
      cc[r] = cn;
      const float hv = ov * tanhf_(cn);
      if (t < T_-1) hstage[(crowl + r)*16 + (lane & 15)] = f2bf(hv);
      else          hT[(size_t)(rb0 + crowl + r)*H_ + colj] = hv;
    }
    if (t < T_-1) {
      __syncthreads();                 // hstage complete
      {  // cooperative coherent write: 256 threads x one aligned 8B store
        const int row = tid >> 2, cg = tid & 3;
        const unsigned long long v = *(const unsigned long long*)&hstage[row*16 + cg*4];
        coh_store8(hb + (size_t)((t+1) & 1)*B_*H_ + (size_t)(rb0 + row)*H_ + s*16 + cg*4, v);
      }
      asm volatile("s_waitcnt vmcnt(0)" ::: "memory");  // own store at coherence point
      __syncthreads();
      if (tid == 0) {
        __hip_atomic_fetch_add(&bar[g*16], 1u, __ATOMIC_RELAXED, __HIP_MEMORY_SCOPE_SYSTEM);
        const unsigned tgt = (unsigned)GRP_WGS * (unsigned)(t + 1);
        while (__hip_atomic_load(&bar[g*16], __ATOMIC_RELAXED, __HIP_MEMORY_SCOPE_SYSTEM) < tgt)
          __builtin_amdgcn_s_sleep(2);
      }
      __syncthreads();
    }
  }
}

// ---------------- phase D: out = h_T @ W_fc^T + b_fc ----------------
__global__ __launch_bounds__(64) void fc_kernel(const uint8_t* __restrict__ ws,
                                                const float* __restrict__ wfc,
                                                const float* __restrict__ bfc,
                                                float* __restrict__ out) {
  const float* hT = (const float*)(ws + OFF_HT);
  const int b = blockIdx.x;
  const int lane = threadIdx.x;
  const float* hr = hT + (size_t)b*H_;
  float hv[12];
  #pragma unroll
  for (int i = 0; i < 12; ++i) hv[i] = hr[lane + i*64];
  for (int o = 0; o < OUT_; ++o) {
    const float* wr = wfc + (size_t)o*H_;
    float sum = 0.f;
    #pragma unroll
    for (int i = 0; i < 12; ++i) sum += hv[i] * wr[lane + i*64];
    #pragma unroll
    for (int off = 32; off; off >>= 1) sum += __shfl_xor(sum, off);
    if (lane == 0) out[(size_t)b*OUT_ + o] = sum + bfc[o];
  }
}

extern "C" void kernel_launch(void* const* d_in, const int* in_sizes, int n_in,
                              void* d_out, int out_size, void* d_ws, size_t ws_size,
                              hipStream_t stream) {
  const float* x   = (const float*)d_in[0];
  const float* wih = (const float*)d_in[1];
  const float* whh = (const float*)d_in[2];
  const float* bih = (const float*)d_in[3];
  const float* bhh = (const float*)d_in[4];
  const float* wfc = (const float*)d_in[5];
  const float* bfc = (const float*)d_in[6];
  uint8_t* ws = (uint8_t*)d_ws;
  float* out = (float*)d_out;

  const bool pre = (ws_size >= WS_PRE);  // deterministic per-session

  prep_kernel<<<dim3(2048), dim3(256), 0, stream>>>(x, wih, whh, ws);
  if (pre) {
    xproj_kernel<<<dim3(256*24), dim3(256), 0, stream>>>(ws);
    lstm_kernel<true><<<dim3(192), dim3(256), 0, stream>>>(ws, bih, bhh);
  } else {
    lstm_kernel<false><<<dim3(192), dim3(256), 0, stream>>>(ws, bih, bhh);
  }
  fc_kernel<<<dim3(256), dim3(64), 0, stream>>>(ws, wfc, bfc, out);
}

// Round 3
// 1335.063 us; speedup vs baseline: 4.3926x; 1.0739x over previous
//
#include <hip/hip_runtime.h>
#include <stdint.h>

#define T_ 128
#define B_ 256
#define D_ 512
#define H_ 768
#define NG 3072   // 4*H
#define OUT_ 60

#define GRP_WGS 48   // strips per batch group; 4 groups x 48 = 192 WGs

using bf16x8 = __attribute__((ext_vector_type(8))) __bf16;
using f32x4  = __attribute__((ext_vector_type(4))) float;
using u32x4  = __attribute__((ext_vector_type(4))) unsigned int;

// ---------------- ws layout (bytes) ----------------
// x packed in MFMA-frag order: chunk ((((t*4+g)*4+w)*16+kf)*64 + hi*16 + l15), 16B each
#define OFF_XPK  ((size_t)0)                        // 33,554,432 B
#define OFF_WIPK (OFF_XPK + (size_t)T_*B_*D_*2)     // W_ih frag-packed, 3,145,728 B
#define OFF_WHH  (OFF_WIPK + (size_t)NG*D_*2)       // W_hh bf16 linear [4H][H]
#define OFF_H    (OFF_WHH + (size_t)NG*H_*2)        // ushort[2*B*H] h double buffer
#define OFF_HT   (OFF_H   + (size_t)2*B_*H_*2)      // float[B*H] final h
#define OFF_BAR  (OFF_HT  + (size_t)B_*H_*4)        // uint[4*48*16] flags, 64B padded
#define OFF_END  (OFF_BAR + 16384)

__device__ __forceinline__ unsigned short f2bf(float f) {
  union { float f; unsigned u; } v; v.f = f;
  unsigned r = (v.u + 0x7fffu + ((v.u >> 16) & 1u)) >> 16;  // RNE
  return (unsigned short)r;
}
__device__ __forceinline__ float sigf(float x) {
  return __builtin_amdgcn_rcpf(1.0f + __expf(-x));
}
__device__ __forceinline__ float tanhf_(float x) {
  return 2.0f * __builtin_amdgcn_rcpf(1.0f + __expf(-2.0f * x)) - 1.0f;
}
// coherent ops at the coherence point (L3): sc0 sc1, no cache-wide flushes
__device__ __forceinline__ void coh_store8(void* p, unsigned long long v) {
  __hip_atomic_store((unsigned long long*)p, v, __ATOMIC_RELAXED, __HIP_MEMORY_SCOPE_SYSTEM);
}
__device__ __forceinline__ void coh_store4(unsigned* p, unsigned v) {
  __hip_atomic_store(p, v, __ATOMIC_RELAXED, __HIP_MEMORY_SCOPE_SYSTEM);
}
__device__ __forceinline__ unsigned coh_load4(const unsigned* p) {
  return __hip_atomic_load(p, __ATOMIC_RELAXED, __HIP_MEMORY_SCOPE_SYSTEM);
}
template<int OFF>
__device__ __forceinline__ u32x4 coh_load16(const void* p) {
  u32x4 r;
  asm volatile("global_load_dwordx4 %0, %1, off offset:%c2 sc0 sc1"
               : "=v"(r) : "v"(p), "i"(OFF) : "memory");
  return r;
}

// ---------------- phase A: pack/convert + init ----------------
__global__ void prep_kernel(const float* __restrict__ x,
                            const float* __restrict__ wihf,
                            const float* __restrict__ whhf,
                            uint8_t* __restrict__ ws) {
  ushort* xpk = (ushort*)(ws + OFF_XPK);
  ushort* wipk = (ushort*)(ws + OFF_WIPK);
  ushort* wh  = (ushort*)(ws + OFF_WHH);
  unsigned* hb = (unsigned*)(ws + OFF_H);
  unsigned* bar = (unsigned*)(ws + OFF_BAR);
  const size_t tid = (size_t)blockIdx.x * blockDim.x + threadIdx.x;
  const size_t nth = (size_t)gridDim.x * blockDim.x;

  // x -> frag-packed bf16 (coalesced f32 reads; 16B scattered writes)
  for (size_t c = tid; c < (size_t)T_*B_*D_/8; c += nth) {
    const float4 v0 = ((const float4*)x)[c*2];
    const float4 v1 = ((const float4*)x)[c*2+1];
    ushort4 o0, o1;
    o0.x=f2bf(v0.x); o0.y=f2bf(v0.y); o0.z=f2bf(v0.z); o0.w=f2bf(v0.w);
    o1.x=f2bf(v1.x); o1.y=f2bf(v1.y); o1.z=f2bf(v1.z); o1.w=f2bf(v1.w);
    const unsigned kf = ((unsigned)c & 63u) >> 2;
    const unsigned hi = (unsigned)c & 3u;
    const unsigned row = (unsigned)(c >> 6);          // t*256 + b
    const unsigned t = row >> 8, b = row & 255u;
    const unsigned g = b >> 6, w = (b >> 4) & 3u, l15 = b & 15u;
    const size_t dst = ((size_t)(((t*4u+g)*4u+w)*16u + kf)*64u + hi*16u + l15) * 8u;
    *(ushort4*)(xpk + dst)     = o0;
    *(ushort4*)(xpk + dst + 4) = o1;
  }
  // W_ih -> frag-packed bf16
  for (size_t c = tid; c < (size_t)NG*D_/8; c += nth) {
    const float4 v0 = ((const float4*)wihf)[c*2];
    const float4 v1 = ((const float4*)wihf)[c*2+1];
    ushort4 o0, o1;
    o0.x=f2bf(v0.x); o0.y=f2bf(v0.y); o0.z=f2bf(v0.z); o0.w=f2bf(v0.w);
    o1.x=f2bf(v1.x); o1.y=f2bf(v1.y); o1.z=f2bf(v1.z); o1.w=f2bf(v1.w);
    const unsigned kf = ((unsigned)c & 63u) >> 2;
    const unsigned hi = (unsigned)c & 3u;
    const unsigned row = (unsigned)(c >> 6);          // gate-row 0..3071
    const unsigned q = row / 768u, rr = row - q*768u;
    const unsigned s = rr >> 4, l15 = rr & 15u;
    const size_t dst = ((size_t)((s*4u+q)*16u + kf)*64u + hi*16u + l15) * 8u;
    *(ushort4*)(wipk + dst)     = o0;
    *(ushort4*)(wipk + dst + 4) = o1;
  }
  // W_hh -> bf16 linear
  for (size_t i = tid; i < (size_t)NG*H_/4; i += nth) {
    float4 v = ((const float4*)whhf)[i];
    ushort4 o; o.x=f2bf(v.x); o.y=f2bf(v.y); o.z=f2bf(v.z); o.w=f2bf(v.w);
    ((ushort4*)wh)[i] = o;
  }
  // zero h double buffer + flags
  for (size_t i = tid; i < (size_t)2*B_*H_/2; i += nth) hb[i] = 0u;
  for (size_t i = tid; i < 4096; i += nth) bar[i] = 0u;
}

// ---------------- phase C: persistent recurrence ----------------
// 192 WGs (all co-resident: 98KB LDS -> 1/CU). Per WG: 64 batch rows x 16 h-cols,
// all 4 gates. W_hh frag-ordered in LDS; h exchanged via L3-coherent 16B loads /
// 8B stores; per-WG flag barrier; next step's x-projection computed under the wait.
__global__ __launch_bounds__(256) void lstm_kernel(uint8_t* __restrict__ ws,
                                                   const float* __restrict__ bih,
                                                   const float* __restrict__ bhh) {
  const uint8_t* __restrict__ xpk = ws + OFF_XPK;
  const uint8_t* __restrict__ wipk = ws + OFF_WIPK;
  const uint8_t* __restrict__ wh  = ws + OFF_WHH;
  ushort* __restrict__ hb = (ushort*)(ws + OFF_H);
  float* __restrict__ hT = (float*)(ws + OFF_HT);
  unsigned* __restrict__ bar = (unsigned*)(ws + OFF_BAR);

  const int tid = threadIdx.x;
  const int lane = tid & 63;
  const int w = tid >> 6;                 // wave 0..3 -> 16 batch rows each
  const int g = blockIdx.x & 3;           // batch group
  const int s = blockIdx.x >> 2;          // h-strip 0..47
  const int rb0 = g * 64;
  const int colj = s*16 + (lane & 15);            // owned h column
  const int arow = rb0 + w*16 + (lane & 15);      // A-frag row (batch)
  const int crowl = w*16 + (lane >> 4)*4;         // C rows base (group-local)
  const int ak = (lane >> 4) * 8;                 // A/B k-slot offset (elements)

  // W_hh in LDS, FRAGMENT order: chunk (kf*4+q)*64+lane -> ds_read_b128 stride-1
  __shared__ ushort wlds[4*24*64*8];   // 96 KB
  __shared__ ushort hstage[64*16];     // 2 KB
  for (int i = 0; i < 24; ++i) {
    const int c = tid + i*256;
    const int l = c & 63, q = (c >> 6) & 3, kf = c >> 8;
    const int grow = q*H_ + s*16 + (l & 15);
    const int gcolB = kf*64 + (l >> 4)*16;
    *(uint4*)((uint8_t*)wlds + (size_t)c*16) =
        *(const uint4*)(wh + (size_t)grow*(H_*2) + gcolB);
  }
  __syncthreads();

  float bias[4];
  #pragma unroll
  for (int q = 0; q < 4; ++q) bias[q] = bih[q*H_ + colj] + bhh[q*H_ + colj];

  float cc[4] = {0.f, 0.f, 0.f, 0.f};
  f32x4 acc[4];
  #pragma unroll
  for (int q = 0; q < 4; ++q) acc[q] = (f32x4){0.f,0.f,0.f,0.f};

  // phase-1 for t=0: acc[q] = x(0) @ W_ih^T   (frag-packed, plain cached loads)
  {
    const u32x4* px = (const u32x4*)(xpk) + ((size_t)((0*4+g)*4+w)*16)*64 + lane;
    const u32x4* pw = (const u32x4*)(wipk) + ((size_t)(s*4)*16)*64 + lane;
    #pragma unroll
    for (int kf = 0; kf < 16; ++kf) {
      const u32x4 xr = px[kf*64];
      const bf16x8 xa = *(const bf16x8*)&xr;
      #pragma unroll
      for (int q = 0; q < 4; ++q) {
        const u32x4 wr = pw[(q*16 + kf)*64];
        acc[q] = __builtin_amdgcn_mfma_f32_16x16x32_bf16(xa, *(const bf16x8*)&wr, acc[q], 0, 0, 0);
      }
    }
  }

  const unsigned myflag = (unsigned)(g*48 + s) * 16u;
  const unsigned pollidx = (unsigned)(g*48 + (lane < 48 ? lane : 47)) * 16u;

  for (int t = 0; t < T_; ++t) {
    // ---- wait for h(t) (flags >= t); t=0 passes immediately ----
    if (w == 0) {
      while (1) {
        const unsigned v = coh_load4(&bar[pollidx]);
        if (__all((int)(v >= (unsigned)t))) break;
        __builtin_amdgcn_s_sleep(1);
      }
    }
    __syncthreads();

    // ---- h A-frags: 24 x 16B coherent loads, one base, one round trip ----
    const ushort* hbase = hb + (size_t)(t & 1)*B_*H_ + (size_t)arow*H_ + ak;
    u32x4 ah[24];
    #define LOADH(i) ah[i] = coh_load16<(i)*64>(hbase)
    LOADH(0); LOADH(1); LOADH(2); LOADH(3); LOADH(4); LOADH(5);
    LOADH(6); LOADH(7); LOADH(8); LOADH(9); LOADH(10); LOADH(11);
    LOADH(12); LOADH(13); LOADH(14); LOADH(15); LOADH(16); LOADH(17);
    LOADH(18); LOADH(19); LOADH(20); LOADH(21); LOADH(22); LOADH(23);
    #undef LOADH
    asm volatile("s_waitcnt vmcnt(0)" ::: "memory");
    __builtin_amdgcn_sched_barrier(0);

    // ---- recurrent MFMA: gates += h @ W_hh^T (LDS frag-ordered, conflict-free) ----
    #pragma unroll
    for (int kf = 0; kf < 24; ++kf) {
      const bf16x8 a = *(const bf16x8*)&ah[kf];
      #pragma unroll
      for (int q = 0; q < 4; ++q) {
        const bf16x8 b = *(const bf16x8*)((const uint8_t*)wlds +
                          (size_t)((kf*4 + q)*64 + lane)*16);
        acc[q] = __builtin_amdgcn_mfma_f32_16x16x32_bf16(a, b, acc[q], 0, 0, 0);
      }
    }

    // ---- activations + state update ----
    float hv4[4];
    #pragma unroll
    for (int r = 0; r < 4; ++r) {
      const float iv = sigf(acc[0][r] + bias[0]);
      const float fv = sigf(acc[1][r] + bias[1]);
      const float gv = tanhf_(acc[2][r] + bias[2]);
      const float ov = sigf(acc[3][r] + bias[3]);
      const float cn = fv * cc[r] + iv * gv;
      cc[r] = cn;
      hv4[r] = ov * tanhf_(cn);
    }
    if (t == T_-1) {
      #pragma unroll
      for (int r = 0; r < 4; ++r)
        hT[(size_t)(rb0 + crowl + r)*H_ + colj] = hv4[r];
      break;
    }
    #pragma unroll
    for (int r = 0; r < 4; ++r)
      hstage[(crowl + r)*16 + (lane & 15)] = f2bf(hv4[r]);
    __syncthreads();
    {  // cooperative coherent h-store: 256 threads x one aligned 8B store
      const int row = tid >> 2, cg = tid & 3;
      const unsigned long long v = *(const unsigned long long*)&hstage[row*16 + cg*4];
      coh_store8(hb + (size_t)((t+1) & 1)*B_*H_ + (size_t)(rb0 + row)*H_ + s*16 + cg*4, v);
    }
    asm volatile("s_waitcnt vmcnt(0)" ::: "memory");  // own stores at coherence point
    __syncthreads();                                   // all 256 threads' stores acked
    if (tid == 0) coh_store4(&bar[myflag], (unsigned)(t + 1));  // arrival

    // ---- phase-1 for t+1 under the barrier: acc = x(t+1) @ W_ih^T ----
    #pragma unroll
    for (int q = 0; q < 4; ++q) acc[q] = (f32x4){0.f,0.f,0.f,0.f};
    {
      const u32x4* px = (const u32x4*)(xpk) + ((size_t)(((t+1)*4+g)*4+w)*16)*64 + lane;
      const u32x4* pw = (const u32x4*)(wipk) + ((size_t)(s*4)*16)*64 + lane;
      #pragma unroll
      for (int kf = 0; kf < 16; ++kf) {
        const u32x4 xr = px[kf*64];
        const bf16x8 xa = *(const bf16x8*)&xr;
        #pragma unroll
        for (int q = 0; q < 4; ++q) {
          const u32x4 wr = pw[(q*16 + kf)*64];
          acc[q] = __builtin_amdgcn_mfma_f32_16x16x32_bf16(xa, *(const bf16x8*)&wr, acc[q], 0, 0, 0);
        }
      }
    }
  }
}

// ---------------- phase D: out = h_T @ W_fc^T + b_fc ----------------
__global__ __launch_bounds__(64) void fc_kernel(const uint8_t* __restrict__ ws,
                                                const float* __restrict__ wfc,
                                                const float* __restrict__ bfc,
                                                float* __restrict__ out) {
  const float* hT = (const float*)(ws + OFF_HT);
  const int b = blockIdx.x;
  const int lane = threadIdx.x;
  const float* hr = hT + (size_t)b*H_;
  float hv[12];
  #pragma unroll
  for (int i = 0; i < 12; ++i) hv[i] = hr[lane + i*64];
  for (int o = 0; o < OUT_; ++o) {
    const float* wr = wfc + (size_t)o*H_;
    float sum = 0.f;
    #pragma unroll
    for (int i = 0; i < 12; ++i) sum += hv[i] * wr[lane + i*64];
    #pragma unroll
    for (int off = 32; off; off >>= 1) sum += __shfl_xor(sum, off);
    if (lane == 0) out[(size_t)b*OUT_ + o] = sum + bfc[o];
  }
}

extern "C" void kernel_launch(void* const* d_in, const int* in_sizes, int n_in,
                              void* d_out, int out_size, void* d_ws, size_t ws_size,
                              hipStream_t stream) {
  const float* x   = (const float*)d_in[0];
  const float* wih = (const float*)d_in[1];
  const float* whh = (const float*)d_in[2];
  const float* bih = (const float*)d_in[3];
  const float* bhh = (const float*)d_in[4];
  const float* wfc = (const float*)d_in[5];
  const float* bfc = (const float*)d_in[6];
  uint8_t* ws = (uint8_t*)d_ws;
  float* out = (float*)d_out;

  prep_kernel<<<dim3(2048), dim3(256), 0, stream>>>(x, wih, whh, ws);
  lstm_kernel<<<dim3(192), dim3(256), 0, stream>>>(ws, bih, bhh);
  fc_kernel<<<dim3(256), dim3(64), 0, stream>>>(ws, wfc, bfc, out);
}